// Round 3
// baseline (1823.004 us; speedup 1.0000x reference)
//
#include <hip/hip_runtime.h>

// ============================================================================
// FilteredTensorProduct: out[n,c] = sum_{a,b} x1[n,a] x2[n,b] ww3j[a,b,c]
//   ww3j = sum_p weights[p] * W3J[p]   (23 SO(3) CG paths, lmax=3, dims 16)
//
// v2b (compile-fixed v2):
//  - __builtin_nontemporal_store via native clang vector (ext_vector_type),
//    not HIP_vector_type float4 (builtin rejects class types).
//  - 2 rows per thread (rows t and t+256 of a 512-row block): 16 outstanding
//    loads/thread, ILP x2 on the FMA chain. __launch_bounds__(256,4) caps at
//    128 VGPR -> 4 waves/SIMD x 2 rows = 8 independent row streams.
//  - coefficients broadcast from LDS (ds_read, uniform address) instead of
//    per-entry v_readlane: removes 359 VALU instrs/row-pair from the VALU
//    pipe, and one coefficient read feeds BOTH rows' FMAs.
//  - schedule regrouped at compile time by unique (a,b) pair: each product
//    a[.]*b[.] computed once (~246 muls instead of 359) and reused across
//    all (c, lo) entries of the pair. Coefficient array is written by
//    cg_setup in schedule order so tp reads it linearly.
//  - first-touch accumulator init (no 16x v_mov zero init).
//  - nontemporal stores: 128 MB of streaming output no longer evicts the
//    256 MB input set from the Infinity Cache between bench iterations.
// ============================================================================

typedef float v4f __attribute__((ext_vector_type(4)));

// ---------------- compile-time sparsity pattern ----------------
struct Tables {
  int npaths;
  int pl1[32], pl2[32], plo[32];
  int nent;
  int pstart[33];
  unsigned char ea[512], eb[512], ec[512], ep[512];
};

constexpr Tables build_tables() {
  Tables t{};
  for (int lo = 0; lo <= 3; ++lo)
    for (int l1 = 0; l1 <= 3; ++l1)
      for (int l2 = 0; l2 <= 3; ++l2) {
        if (((l1 + l2 + lo) & 1) != 0) continue;           // parity rule
        int lmin = l1 > l2 ? l1 - l2 : l2 - l1;
        if (lo > l1 + l2 || lo < lmin) continue;           // triangle rule
        int p = t.npaths;
        t.pl1[p] = l1; t.pl2[p] = l2; t.plo[p] = lo;
        t.pstart[p] = t.nent;
        int o1 = l1 * l1, o2 = l2 * l2, oo = lo * lo;
        for (int m1 = -l1; m1 <= l1; ++m1)
          for (int m2 = -l2; m2 <= l2; ++m2) {
            int cand[2] = {0, 0}; int nc = 0;
            if (m1 == 0) cand[nc++] = m2;                  // Y_{l,0} has no phi dep
            else if (m2 == 0) cand[nc++] = m1;
            else {
              int u = m1 < 0 ? -m1 : m1, v = m2 < 0 ? -m2 : m2;
              int d = u > v ? u - v : v - u;
              if ((m1 > 0) == (m2 > 0)) {                  // cos*cos or sin*sin -> cos
                cand[nc++] = u + v; cand[nc++] = d;
              } else {                                     // sin*cos -> sin
                cand[nc++] = -(u + v);
                if (d) cand[nc++] = -d;                    // sin(0) == 0
              }
            }
            for (int q = 0; q < nc; ++q) {
              int m3 = cand[q];
              int am3 = m3 < 0 ? -m3 : m3;
              if (am3 <= lo) {
                t.ea[t.nent] = (unsigned char)(o1 + l1 + m1);
                t.eb[t.nent] = (unsigned char)(o2 + l2 + m2);
                t.ec[t.nent] = (unsigned char)(oo + lo + m3);
                t.ep[t.nent] = (unsigned char)p;
                ++t.nent;
              }
            }
          }
        ++t.npaths;
        t.pstart[t.npaths] = t.nent;
      }
  return t;
}

constexpr Tables TBL = build_tables();

// ---------------- compile-time schedule: group entries by (a,b) pair -------
struct Sched {
  int npair;
  int nent;
  unsigned char pa[320], pb[320];   // per unique (a,b) pair
  short pstart[321];                // slot range per pair
  unsigned char sc[512];            // output index c per slot
  unsigned char sp[512];            // path id per slot (for cg_setup)
  unsigned char sa[512], sb[512];   // a,b per slot (for cg_setup)
  bool firstc[512];                 // slot is globally first touch of its c
};

constexpr Sched build_sched() {
  Sched s{};
  int pos = 0;
  bool seen[16] = {};
  for (int a = 0; a < 16; ++a)
    for (int b = 0; b < 16; ++b) {
      int cnt = 0;
      for (int e = 0; e < TBL.nent; ++e) {
        if ((int)TBL.ea[e] == a && (int)TBL.eb[e] == b) {
          if (cnt == 0) {
            s.pa[s.npair] = (unsigned char)a;
            s.pb[s.npair] = (unsigned char)b;
            s.pstart[s.npair] = (short)pos;
          }
          s.sc[pos] = TBL.ec[e];
          s.sp[pos] = TBL.ep[e];
          s.sa[pos] = (unsigned char)a;
          s.sb[pos] = (unsigned char)b;
          s.firstc[pos] = !seen[TBL.ec[e]];
          seen[TBL.ec[e]] = true;
          ++cnt; ++pos;
        }
      }
      if (cnt) { ++s.npair; s.pstart[s.npair] = (short)pos; }
    }
  s.nent = pos;
  return s;
}

constexpr Sched SCH = build_sched();
constexpr int NENT = SCH.nent;
static_assert(SCH.nent == TBL.nent, "schedule must cover all entries");
static_assert(SCH.nent <= 512 && SCH.npair <= 320, "table overflow");

// ---------------- device CG math (fp64, transcribes reference) -------------
__device__ __constant__ double FACT[11] = {
    1., 1., 2., 6., 24., 120., 720., 5040., 40320., 362880., 3628800.};

struct cplx { double re, im; };

__device__ inline double su2_cg(int j1, int m1, int j2, int m2, int j3, int m3) {
  if (m3 != m1 + m2) return 0.0;
  int vmin = -j1 + j2 + m3;
  if (-j1 + m1 > vmin) vmin = -j1 + m1;
  if (0 > vmin) vmin = 0;
  int vmax = j2 + j3 + m1;
  if (j3 - j1 + j2 < vmax) vmax = j3 - j1 + j2;
  if (j3 + m3 < vmax) vmax = j3 + m3;
  double C = (2.0 * j3 + 1.0) *
             (FACT[j3 + j1 - j2] * FACT[j3 - j1 + j2] * FACT[j1 + j2 - j3] *
              FACT[j3 + m3] * FACT[j3 - m3]) /
             (FACT[j1 + j2 + j3 + 1] * FACT[j1 - m1] * FACT[j1 + m1] *
              FACT[j2 - m2] * FACT[j2 + m2]);
  double S = 0.0;
  for (int v = vmin; v <= vmax; ++v) {
    double t = (FACT[j2 + j3 + m1 - v] * FACT[j1 - m1 + v]) /
               (FACT[v] * FACT[j3 - j1 + j2 - v] * FACT[j3 + m3 - v] *
                FACT[v + j1 - j2 - m3]);
    S += (((v + j2 + m2) & 1) ? -1.0 : 1.0) * t;
  }
  return sqrt(C) * S;
}

// q[l+m, l+-|m|] of _change_basis_real_to_complex, incl. global (-i)^l phase.
__device__ inline cplx Qmat(int l, int r, int c) {
  int m = r - l, mc = c - l;
  const double is2 = 0.70710678118654752440;
  double re = 0.0, im = 0.0;
  if (m < 0) {
    if (mc == -m) re = is2;
    else if (mc == m) im = -is2;
  } else if (m == 0) {
    if (mc == 0) re = 1.0;
  } else {
    double s = (m & 1) ? -is2 : is2;
    if (mc == m) re = s;
    else if (mc == -m) im = s;
  }
  cplx out;
  switch (l & 3) {                   // multiply by (-i)^l
    case 0: out.re = re;  out.im = im;  break;
    case 1: out.re = im;  out.im = -re; break;
    case 2: out.re = -re; out.im = -im; break;
    default: out.re = -im; out.im = re; break;
  }
  return out;
}

// One block per path. Computes real-basis CG values and writes
// weights[p]*sqrt(2lo+1)*Creal into the SCHEDULE-ORDERED coefficient slots.
__global__ void cg_setup_kernel(const float* __restrict__ weights,
                                float* __restrict__ wwc) {
  const int p = blockIdx.x;
  const int l1 = TBL.pl1[p], l2 = TBL.pl2[p], lo = TBL.plo[p];
  const int n1 = 2 * l1 + 1, n2 = 2 * l2 + 1, n3 = 2 * lo + 1;
  const int tot = n1 * n2 * n3;
  const int tid = (int)threadIdx.x;
  const int bd = (int)blockDim.x;

  __shared__ double Cs[343];
  __shared__ double Vr[343], Vi[343];
  __shared__ double Ur[343], Ui[343];
  __shared__ double Rr[343];

  // stage 0: SU(2) CG tensor Cs[i,k,n]
  for (int idx = tid; idx < tot; idx += bd) {
    int i = idx / (n2 * n3), r = idx % (n2 * n3);
    int k = r / n3, nn = r % n3;
    Cs[idx] = su2_cg(l1, i - l1, l2, k - l2, lo, nn - lo);
  }
  __syncthreads();

  // stage A: V[i,k,m] = sum_n Cs[i,k,n] * conj(Q3[n,m])
  for (int idx = tid; idx < tot; idx += bd) {
    int i = idx / (n2 * n3), r = idx % (n2 * n3);
    int k = r / n3, m = r % n3;
    double vr = 0.0, vi = 0.0;
    for (int nn = 0; nn < n3; ++nn) {
      double c = Cs[(i * n2 + k) * n3 + nn];
      cplx q = Qmat(lo, nn, m);
      vr += c * q.re;
      vi -= c * q.im;
    }
    Vr[idx] = vr; Vi[idx] = vi;
  }
  __syncthreads();

  // stage B: U[i,l,m] = sum_k Q2[k,l] * V[i,k,m]
  for (int idx = tid; idx < tot; idx += bd) {
    int i = idx / (n2 * n3), r = idx % (n2 * n3);
    int l = r / n3, m = r % n3;
    double ur = 0.0, ui = 0.0;
    for (int k = 0; k < n2; ++k) {
      cplx q = Qmat(l2, k, l);
      double vr = Vr[(i * n2 + k) * n3 + m];
      double vi = Vi[(i * n2 + k) * n3 + m];
      ur += q.re * vr - q.im * vi;
      ui += q.re * vi + q.im * vr;
    }
    Ur[idx] = ur; Ui[idx] = ui;
  }
  __syncthreads();

  // stage C: R[j,l,m] = Re( sum_i Q1[i,j] * U[i,l,m] )
  for (int idx = tid; idx < tot; idx += bd) {
    int j = idx / (n2 * n3), r = idx % (n2 * n3);
    int l = r / n3, m = r % n3;
    double rr = 0.0;
    for (int i = 0; i < n1; ++i) {
      cplx q = Qmat(l1, i, j);
      rr += q.re * Ur[(i * n2 + l) * n3 + m] - q.im * Ui[(i * n2 + l) * n3 + m];
    }
    Rr[idx] = rr;
  }
  __syncthreads();

  // write schedule-ordered coefficients belonging to this path
  const double wsc = (double)weights[p] * sqrt(2.0 * lo + 1.0);
  const int o1 = l1 * l1, o2 = l2 * l2, oo = lo * lo;
  for (int s = tid; s < NENT; s += bd) {
    if ((int)SCH.sp[s] != p) continue;
    int i = (int)SCH.sa[s] - o1;
    int j = (int)SCH.sb[s] - o2;
    int k = (int)SCH.sc[s] - oo;
    wwc[s] = (float)(wsc * Rr[(i * n2 + j) * n3 + k]);
  }
}

// ---------------- main contraction kernel ----------------
// 2 rows per thread: r0 = block*512 + tid, r1 = r0 + 256.
__global__ __launch_bounds__(256, 4) void tp_kernel(
    const float* __restrict__ x1, const float* __restrict__ x2,
    const float* __restrict__ wwc, float* __restrict__ out, int n) {
  __shared__ float ws[NENT];
  for (int i = (int)threadIdx.x; i < NENT; i += 256) ws[i] = wwc[i];
  __syncthreads();

  const int r0 = (int)blockIdx.x * 512 + (int)threadIdx.x;
  if (r0 >= n) return;
  const int r1 = r0 + 256;
  const bool h1 = (r1 < n);
  const int r1a = h1 ? r1 : r0;          // clamp: loads valid, store guarded

  const v4f* X1a = reinterpret_cast<const v4f*>(x1) + (size_t)r0 * 4;
  const v4f* X2a = reinterpret_cast<const v4f*>(x2) + (size_t)r0 * 4;
  const v4f* X1b = reinterpret_cast<const v4f*>(x1) + (size_t)r1a * 4;
  const v4f* X2b = reinterpret_cast<const v4f*>(x2) + (size_t)r1a * 4;

  float a0[16], b0[16], a1[16], b1[16];
#pragma unroll
  for (int q = 0; q < 4; ++q) {
    v4f t = X1a[q];
    a0[4 * q + 0] = t.x; a0[4 * q + 1] = t.y; a0[4 * q + 2] = t.z; a0[4 * q + 3] = t.w;
    v4f u = X2a[q];
    b0[4 * q + 0] = u.x; b0[4 * q + 1] = u.y; b0[4 * q + 2] = u.z; b0[4 * q + 3] = u.w;
    v4f v = X1b[q];
    a1[4 * q + 0] = v.x; a1[4 * q + 1] = v.y; a1[4 * q + 2] = v.z; a1[4 * q + 3] = v.w;
    v4f w = X2b[q];
    b1[4 * q + 0] = w.x; b1[4 * q + 1] = w.y; b1[4 * q + 2] = w.z; b1[4 * q + 3] = w.w;
  }

  float acc0[16], acc1[16];   // first-touch initialized via SCH.firstc

#pragma unroll
  for (int u = 0; u < SCH.npair; ++u) {
    const float t0 = a0[SCH.pa[u]] * b0[SCH.pb[u]];
    const float t1 = a1[SCH.pa[u]] * b1[SCH.pb[u]];
#pragma unroll
    for (int s = SCH.pstart[u]; s < SCH.pstart[u + 1]; ++s) {
      const float w = ws[s];             // LDS broadcast (uniform address)
      const int c = SCH.sc[s];
      if (SCH.firstc[s]) {               // constant-folds after unroll
        acc0[c] = w * t0;
        acc1[c] = w * t1;
      } else {
        acc0[c] = fmaf(w, t0, acc0[c]);
        acc1[c] = fmaf(w, t1, acc1[c]);
      }
    }
  }

  v4f* O0 = reinterpret_cast<v4f*>(out) + (size_t)r0 * 4;
#pragma unroll
  for (int q = 0; q < 4; ++q) {
    v4f o;
    o.x = acc0[4 * q + 0]; o.y = acc0[4 * q + 1];
    o.z = acc0[4 * q + 2]; o.w = acc0[4 * q + 3];
    __builtin_nontemporal_store(o, &O0[q]);
  }
  if (h1) {
    v4f* O1 = reinterpret_cast<v4f*>(out) + (size_t)r1 * 4;
#pragma unroll
    for (int q = 0; q < 4; ++q) {
      v4f o;
      o.x = acc1[4 * q + 0]; o.y = acc1[4 * q + 1];
      o.z = acc1[4 * q + 2]; o.w = acc1[4 * q + 3];
      __builtin_nontemporal_store(o, &O1[q]);
    }
  }
}

// ---------------- launch ----------------
extern "C" void kernel_launch(void* const* d_in, const int* in_sizes, int n_in,
                              void* d_out, int out_size, void* d_ws,
                              size_t ws_size, hipStream_t stream) {
  const float* x1 = (const float*)d_in[0];
  const float* x2 = (const float*)d_in[1];
  const float* w  = (const float*)d_in[2];
  float* out = (float*)d_out;
  float* wwc = (float*)d_ws;   // NENT compacted coefficients (schedule order)

  const int n = in_sizes[0] / 16;

  // 1) compute compacted ww3j coefficients (23 tiny blocks)
  cg_setup_kernel<<<dim3(TBL.npaths), dim3(256), 0, stream>>>(w, wwc);

  // 2) sparse per-row contraction, 2 rows/thread
  const int grid = (n + 511) / 512;
  tp_kernel<<<dim3(grid), dim3(256), 0, stream>>>(x1, x2, wwc, out, n);
}

// Round 4
// 1778.383 us; speedup vs baseline: 1.0251x; 1.0251x over previous
//
#include <hip/hip_runtime.h>
#include <utility>

// ============================================================================
// FilteredTensorProduct: out[n,c] = sum_{a,b} x1[n,a] x2[n,b] ww3j[a,b,c]
//   ww3j = sum_p weights[p] * W3J[p]   (23 SO(3) CG paths, lmax=3, dims 16)
//
// v3: fix v2's scratch-spill catastrophe (VGPR=64, 5.7GB scratch traffic).
//  ROOT CAUSE: nested schedule loop (outer over pairs, inner over entries,
//  data-dependent bounds) failed to fully unroll -> runtime array indexing ->
//  all 96 per-thread floats demoted to scratch (rule #20).
//  FIX: flat per-entry schedule driven by a fold expression over
//  std::make_integer_sequence<int, NENT>. Every index (a,b,c) and every
//  newpair/firstc flag is a constexpr template parameter -> unroll and
//  constant indexing are guaranteed; SROA keeps arrays in VGPRs.
//
//  Retained from v2: 2 rows/thread (ILP/MLP x2), LDS coefficient broadcast
//  (one ds_read feeds both rows' FMAs), pair-grouped products (~246 muls
//  instead of 359), first-touch accumulator init, nontemporal v4f stores.
// ============================================================================

typedef float v4f __attribute__((ext_vector_type(4)));

// ---------------- compile-time sparsity pattern ----------------
struct Tables {
  int npaths;
  int pl1[32], pl2[32], plo[32];
  int nent;
  int pstart[33];
  unsigned char ea[512], eb[512], ec[512], ep[512];
};

constexpr Tables build_tables() {
  Tables t{};
  for (int lo = 0; lo <= 3; ++lo)
    for (int l1 = 0; l1 <= 3; ++l1)
      for (int l2 = 0; l2 <= 3; ++l2) {
        if (((l1 + l2 + lo) & 1) != 0) continue;           // parity rule
        int lmin = l1 > l2 ? l1 - l2 : l2 - l1;
        if (lo > l1 + l2 || lo < lmin) continue;           // triangle rule
        int p = t.npaths;
        t.pl1[p] = l1; t.pl2[p] = l2; t.plo[p] = lo;
        t.pstart[p] = t.nent;
        int o1 = l1 * l1, o2 = l2 * l2, oo = lo * lo;
        for (int m1 = -l1; m1 <= l1; ++m1)
          for (int m2 = -l2; m2 <= l2; ++m2) {
            int cand[2] = {0, 0}; int nc = 0;
            if (m1 == 0) cand[nc++] = m2;                  // Y_{l,0} has no phi dep
            else if (m2 == 0) cand[nc++] = m1;
            else {
              int u = m1 < 0 ? -m1 : m1, v = m2 < 0 ? -m2 : m2;
              int d = u > v ? u - v : v - u;
              if ((m1 > 0) == (m2 > 0)) {                  // cos*cos or sin*sin -> cos
                cand[nc++] = u + v; cand[nc++] = d;
              } else {                                     // sin*cos -> sin
                cand[nc++] = -(u + v);
                if (d) cand[nc++] = -d;                    // sin(0) == 0
              }
            }
            for (int q = 0; q < nc; ++q) {
              int m3 = cand[q];
              int am3 = m3 < 0 ? -m3 : m3;
              if (am3 <= lo) {
                t.ea[t.nent] = (unsigned char)(o1 + l1 + m1);
                t.eb[t.nent] = (unsigned char)(o2 + l2 + m2);
                t.ec[t.nent] = (unsigned char)(oo + lo + m3);
                t.ep[t.nent] = (unsigned char)p;
                ++t.nent;
              }
            }
          }
        ++t.npaths;
        t.pstart[t.npaths] = t.nent;
      }
  return t;
}

constexpr Tables TBL = build_tables();

// -------- flat compile-time schedule, grouped by unique (a,b) pair --------
struct Sched {
  int nent;
  unsigned char sa[512], sb[512], sc[512], sp[512];
  bool newpair[512];                // slot starts a new (a,b) product
  bool firstc[512];                 // slot is globally first touch of its c
};

constexpr Sched build_sched() {
  Sched s{};
  int pos = 0;
  bool seen[16] = {};
  for (int a = 0; a < 16; ++a)
    for (int b = 0; b < 16; ++b) {
      bool first_of_pair = true;
      for (int e = 0; e < TBL.nent; ++e) {
        if ((int)TBL.ea[e] == a && (int)TBL.eb[e] == b) {
          s.sa[pos] = (unsigned char)a;
          s.sb[pos] = (unsigned char)b;
          s.sc[pos] = TBL.ec[e];
          s.sp[pos] = TBL.ep[e];
          s.newpair[pos] = first_of_pair;
          s.firstc[pos] = !seen[TBL.ec[e]];
          seen[TBL.ec[e]] = true;
          first_of_pair = false;
          ++pos;
        }
      }
    }
  s.nent = pos;
  return s;
}

constexpr Sched SCH = build_sched();
constexpr int NENT = SCH.nent;
static_assert(SCH.nent == TBL.nent, "schedule must cover all entries");
static_assert(SCH.nent <= 512, "table overflow");

// ---------------- device CG math (fp64, transcribes reference) -------------
__device__ __constant__ double FACT[11] = {
    1., 1., 2., 6., 24., 120., 720., 5040., 40320., 362880., 3628800.};

struct cplx { double re, im; };

__device__ inline double su2_cg(int j1, int m1, int j2, int m2, int j3, int m3) {
  if (m3 != m1 + m2) return 0.0;
  int vmin = -j1 + j2 + m3;
  if (-j1 + m1 > vmin) vmin = -j1 + m1;
  if (0 > vmin) vmin = 0;
  int vmax = j2 + j3 + m1;
  if (j3 - j1 + j2 < vmax) vmax = j3 - j1 + j2;
  if (j3 + m3 < vmax) vmax = j3 + m3;
  double C = (2.0 * j3 + 1.0) *
             (FACT[j3 + j1 - j2] * FACT[j3 - j1 + j2] * FACT[j1 + j2 - j3] *
              FACT[j3 + m3] * FACT[j3 - m3]) /
             (FACT[j1 + j2 + j3 + 1] * FACT[j1 - m1] * FACT[j1 + m1] *
              FACT[j2 - m2] * FACT[j2 + m2]);
  double S = 0.0;
  for (int v = vmin; v <= vmax; ++v) {
    double t = (FACT[j2 + j3 + m1 - v] * FACT[j1 - m1 + v]) /
               (FACT[v] * FACT[j3 - j1 + j2 - v] * FACT[j3 + m3 - v] *
                FACT[v + j1 - j2 - m3]);
    S += (((v + j2 + m2) & 1) ? -1.0 : 1.0) * t;
  }
  return sqrt(C) * S;
}

// q[l+m, l+-|m|] of _change_basis_real_to_complex, incl. global (-i)^l phase.
__device__ inline cplx Qmat(int l, int r, int c) {
  int m = r - l, mc = c - l;
  const double is2 = 0.70710678118654752440;
  double re = 0.0, im = 0.0;
  if (m < 0) {
    if (mc == -m) re = is2;
    else if (mc == m) im = -is2;
  } else if (m == 0) {
    if (mc == 0) re = 1.0;
  } else {
    double s = (m & 1) ? -is2 : is2;
    if (mc == m) re = s;
    else if (mc == -m) im = s;
  }
  cplx out;
  switch (l & 3) {                   // multiply by (-i)^l
    case 0: out.re = re;  out.im = im;  break;
    case 1: out.re = im;  out.im = -re; break;
    case 2: out.re = -re; out.im = -im; break;
    default: out.re = -im; out.im = re; break;
  }
  return out;
}

// One block per path. Computes real-basis CG values and writes
// weights[p]*sqrt(2lo+1)*Creal into the SCHEDULE-ORDERED coefficient slots.
__global__ void cg_setup_kernel(const float* __restrict__ weights,
                                float* __restrict__ wwc) {
  const int p = blockIdx.x;
  const int l1 = TBL.pl1[p], l2 = TBL.pl2[p], lo = TBL.plo[p];
  const int n1 = 2 * l1 + 1, n2 = 2 * l2 + 1, n3 = 2 * lo + 1;
  const int tot = n1 * n2 * n3;
  const int tid = (int)threadIdx.x;
  const int bd = (int)blockDim.x;

  __shared__ double Cs[343];
  __shared__ double Vr[343], Vi[343];
  __shared__ double Ur[343], Ui[343];
  __shared__ double Rr[343];

  // stage 0: SU(2) CG tensor Cs[i,k,n]
  for (int idx = tid; idx < tot; idx += bd) {
    int i = idx / (n2 * n3), r = idx % (n2 * n3);
    int k = r / n3, nn = r % n3;
    Cs[idx] = su2_cg(l1, i - l1, l2, k - l2, lo, nn - lo);
  }
  __syncthreads();

  // stage A: V[i,k,m] = sum_n Cs[i,k,n] * conj(Q3[n,m])
  for (int idx = tid; idx < tot; idx += bd) {
    int i = idx / (n2 * n3), r = idx % (n2 * n3);
    int k = r / n3, m = r % n3;
    double vr = 0.0, vi = 0.0;
    for (int nn = 0; nn < n3; ++nn) {
      double c = Cs[(i * n2 + k) * n3 + nn];
      cplx q = Qmat(lo, nn, m);
      vr += c * q.re;
      vi -= c * q.im;
    }
    Vr[idx] = vr; Vi[idx] = vi;
  }
  __syncthreads();

  // stage B: U[i,l,m] = sum_k Q2[k,l] * V[i,k,m]
  for (int idx = tid; idx < tot; idx += bd) {
    int i = idx / (n2 * n3), r = idx % (n2 * n3);
    int l = r / n3, m = r % n3;
    double ur = 0.0, ui = 0.0;
    for (int k = 0; k < n2; ++k) {
      cplx q = Qmat(l2, k, l);
      double vr = Vr[(i * n2 + k) * n3 + m];
      double vi = Vi[(i * n2 + k) * n3 + m];
      ur += q.re * vr - q.im * vi;
      ui += q.re * vi + q.im * vr;
    }
    Ur[idx] = ur; Ui[idx] = ui;
  }
  __syncthreads();

  // stage C: R[j,l,m] = Re( sum_i Q1[i,j] * U[i,l,m] )
  for (int idx = tid; idx < tot; idx += bd) {
    int j = idx / (n2 * n3), r = idx % (n2 * n3);
    int l = r / n3, m = r % n3;
    double rr = 0.0;
    for (int i = 0; i < n1; ++i) {
      cplx q = Qmat(l1, i, j);
      rr += q.re * Ur[(i * n2 + l) * n3 + m] - q.im * Ui[(i * n2 + l) * n3 + m];
    }
    Rr[idx] = rr;
  }
  __syncthreads();

  // write schedule-ordered coefficients belonging to this path
  const double wsc = (double)weights[p] * sqrt(2.0 * lo + 1.0);
  const int o1 = l1 * l1, o2 = l2 * l2, oo = lo * lo;
  for (int s = tid; s < NENT; s += bd) {
    if ((int)SCH.sp[s] != p) continue;
    int i = (int)SCH.sa[s] - o1;
    int j = (int)SCH.sb[s] - o2;
    int k = (int)SCH.sc[s] - oo;
    wwc[s] = (float)(wsc * Rr[(i * n2 + j) * n3 + k]);
  }
}

// ---------------- main contraction: guaranteed-unrolled schedule -----------
// Every index is a constexpr template parameter -> SROA keeps arrays in VGPRs.
template <int E>
__device__ __forceinline__ void tp_step(const float (&a0)[16], const float (&b0)[16],
                                        const float (&a1)[16], const float (&b1)[16],
                                        float (&acc0)[16], float (&acc1)[16],
                                        const float* __restrict__ ws,
                                        float& t0, float& t1) {
  constexpr int A = (int)SCH.sa[E];
  constexpr int B = (int)SCH.sb[E];
  constexpr int C = (int)SCH.sc[E];
  if constexpr (SCH.newpair[E]) {
    t0 = a0[A] * b0[B];
    t1 = a1[A] * b1[B];
  }
  const float w = ws[E];              // LDS broadcast, immediate offset
  if constexpr (SCH.firstc[E]) {
    acc0[C] = w * t0;
    acc1[C] = w * t1;
  } else {
    acc0[C] = fmaf(w, t0, acc0[C]);
    acc1[C] = fmaf(w, t1, acc1[C]);
  }
}

template <int... Es>
__device__ __forceinline__ void tp_contract(std::integer_sequence<int, Es...>,
                                            const float (&a0)[16], const float (&b0)[16],
                                            const float (&a1)[16], const float (&b1)[16],
                                            float (&acc0)[16], float (&acc1)[16],
                                            const float* __restrict__ ws,
                                            float& t0, float& t1) {
  (tp_step<Es>(a0, b0, a1, b1, acc0, acc1, ws, t0, t1), ...);
}

// 2 rows per thread: r0 = block*512 + tid, r1 = r0 + 256.
__global__ __launch_bounds__(256, 4) void tp_kernel(
    const float* __restrict__ x1, const float* __restrict__ x2,
    const float* __restrict__ wwc, float* __restrict__ out, int n) {
  __shared__ float ws[NENT];
  for (int i = (int)threadIdx.x; i < NENT; i += 256) ws[i] = wwc[i];
  __syncthreads();

  const int r0 = (int)blockIdx.x * 512 + (int)threadIdx.x;
  if (r0 >= n) return;
  const int r1 = r0 + 256;
  const bool h1 = (r1 < n);
  const int r1a = h1 ? r1 : r0;          // clamp: loads valid, store guarded

  const v4f* X1a = reinterpret_cast<const v4f*>(x1) + (size_t)r0 * 4;
  const v4f* X2a = reinterpret_cast<const v4f*>(x2) + (size_t)r0 * 4;
  const v4f* X1b = reinterpret_cast<const v4f*>(x1) + (size_t)r1a * 4;
  const v4f* X2b = reinterpret_cast<const v4f*>(x2) + (size_t)r1a * 4;

  float a0[16], b0[16], a1[16], b1[16];
#pragma unroll
  for (int q = 0; q < 4; ++q) {
    v4f t = X1a[q];
    a0[4 * q + 0] = t.x; a0[4 * q + 1] = t.y; a0[4 * q + 2] = t.z; a0[4 * q + 3] = t.w;
    v4f u = X2a[q];
    b0[4 * q + 0] = u.x; b0[4 * q + 1] = u.y; b0[4 * q + 2] = u.z; b0[4 * q + 3] = u.w;
    v4f v = X1b[q];
    a1[4 * q + 0] = v.x; a1[4 * q + 1] = v.y; a1[4 * q + 2] = v.z; a1[4 * q + 3] = v.w;
    v4f w = X2b[q];
    b1[4 * q + 0] = w.x; b1[4 * q + 1] = w.y; b1[4 * q + 2] = w.z; b1[4 * q + 3] = w.w;
  }

  float acc0[16], acc1[16];   // first-touch initialized via SCH.firstc
  float t0 = 0.0f, t1 = 0.0f;

  tp_contract(std::make_integer_sequence<int, NENT>{}, a0, b0, a1, b1, acc0,
              acc1, ws, t0, t1);

  v4f* O0 = reinterpret_cast<v4f*>(out) + (size_t)r0 * 4;
#pragma unroll
  for (int q = 0; q < 4; ++q) {
    v4f o;
    o.x = acc0[4 * q + 0]; o.y = acc0[4 * q + 1];
    o.z = acc0[4 * q + 2]; o.w = acc0[4 * q + 3];
    __builtin_nontemporal_store(o, &O0[q]);
  }
  if (h1) {
    v4f* O1 = reinterpret_cast<v4f*>(out) + (size_t)r1 * 4;
#pragma unroll
    for (int q = 0; q < 4; ++q) {
      v4f o;
      o.x = acc1[4 * q + 0]; o.y = acc1[4 * q + 1];
      o.z = acc1[4 * q + 2]; o.w = acc1[4 * q + 3];
      __builtin_nontemporal_store(o, &O1[q]);
    }
  }
}

// ---------------- launch ----------------
extern "C" void kernel_launch(void* const* d_in, const int* in_sizes, int n_in,
                              void* d_out, int out_size, void* d_ws,
                              size_t ws_size, hipStream_t stream) {
  const float* x1 = (const float*)d_in[0];
  const float* x2 = (const float*)d_in[1];
  const float* w  = (const float*)d_in[2];
  float* out = (float*)d_out;
  float* wwc = (float*)d_ws;   // NENT compacted coefficients (schedule order)

  const int n = in_sizes[0] / 16;

  // 1) compute compacted ww3j coefficients (23 tiny blocks)
  cg_setup_kernel<<<dim3(TBL.npaths), dim3(256), 0, stream>>>(w, wwc);

  // 2) sparse per-row contraction, 2 rows/thread, guaranteed-unrolled schedule
  const int grid = (n + 511) / 512;
  tp_kernel<<<dim3(grid), dim3(256), 0, stream>>>(x1, x2, wwc, out, n);
}

// Round 5
// 388.773 us; speedup vs baseline: 4.6891x; 4.5743x over previous
//
#include <hip/hip_runtime.h>

// ============================================================================
// FilteredTensorProduct: out[n,c] = sum_{a,b} x1[n,a] x2[n,b] ww3j[a,b,c]
//   ww3j = sum_p weights[p] * W3J[p]   (23 SO(3) CG paths, lmax=3, dims 16)
//
// v4: revert to the PROVEN v1 register structure (1 row/thread, 3 arrays,
// flat #pragma unroll loop -> SROA promotes; v1 measured 80 VGPR, no
// scratch, 113us). v2/v3's 2-row/6-array variants were demoted to scratch
// wholesale (VGPR=64, 5.6GB scratch traffic, 1.6ms) regardless of indexing
// style -> the AMDGPU alloca promoter gives up above a footprint budget.
// Deltas vs v1, none of which add arrays:
//  - coefficients read directly as wwc[e] at compile-time offsets
//    (wave-uniform, read-only __restrict__ -> scalar s_load batches into
//    SGPRs). Replaces 359 v_readlane VALU ops. No LDS, no syncthreads.
//  - flat schedule grouped by unique (a,b) pair with constexpr newpair
//    flags: 246 muls instead of 359 (one product reused across all c of
//    the pair). Same constant-folding pattern v1 proved works.
//  - first-touch accumulator init via constexpr firstc flags.
//  - nontemporal v4f stores: 128MB output stream doesn't evict the 256MB
//    input set from the Infinity Cache.
// ============================================================================

typedef float v4f __attribute__((ext_vector_type(4)));

// ---------------- compile-time sparsity pattern ----------------
struct Tables {
  int npaths;
  int pl1[32], pl2[32], plo[32];
  int nent;
  int pstart[33];
  unsigned char ea[512], eb[512], ec[512], ep[512];
};

constexpr Tables build_tables() {
  Tables t{};
  for (int lo = 0; lo <= 3; ++lo)
    for (int l1 = 0; l1 <= 3; ++l1)
      for (int l2 = 0; l2 <= 3; ++l2) {
        if (((l1 + l2 + lo) & 1) != 0) continue;           // parity rule
        int lmin = l1 > l2 ? l1 - l2 : l2 - l1;
        if (lo > l1 + l2 || lo < lmin) continue;           // triangle rule
        int p = t.npaths;
        t.pl1[p] = l1; t.pl2[p] = l2; t.plo[p] = lo;
        t.pstart[p] = t.nent;
        int o1 = l1 * l1, o2 = l2 * l2, oo = lo * lo;
        for (int m1 = -l1; m1 <= l1; ++m1)
          for (int m2 = -l2; m2 <= l2; ++m2) {
            int cand[2] = {0, 0}; int nc = 0;
            if (m1 == 0) cand[nc++] = m2;                  // Y_{l,0} has no phi dep
            else if (m2 == 0) cand[nc++] = m1;
            else {
              int u = m1 < 0 ? -m1 : m1, v = m2 < 0 ? -m2 : m2;
              int d = u > v ? u - v : v - u;
              if ((m1 > 0) == (m2 > 0)) {                  // cos*cos or sin*sin -> cos
                cand[nc++] = u + v; cand[nc++] = d;
              } else {                                     // sin*cos -> sin
                cand[nc++] = -(u + v);
                if (d) cand[nc++] = -d;                    // sin(0) == 0
              }
            }
            for (int q = 0; q < nc; ++q) {
              int m3 = cand[q];
              int am3 = m3 < 0 ? -m3 : m3;
              if (am3 <= lo) {
                t.ea[t.nent] = (unsigned char)(o1 + l1 + m1);
                t.eb[t.nent] = (unsigned char)(o2 + l2 + m2);
                t.ec[t.nent] = (unsigned char)(oo + lo + m3);
                t.ep[t.nent] = (unsigned char)p;
                ++t.nent;
              }
            }
          }
        ++t.npaths;
        t.pstart[t.npaths] = t.nent;
      }
  return t;
}

constexpr Tables TBL = build_tables();

// -------- flat compile-time schedule, grouped by unique (a,b) pair --------
struct Sched {
  int nent;
  unsigned char sa[512], sb[512], sc[512], sp[512];
  bool newpair[512];                // slot starts a new (a,b) product
  bool firstc[512];                 // slot is globally first touch of its c
};

constexpr Sched build_sched() {
  Sched s{};
  int pos = 0;
  bool seen[16] = {};
  for (int a = 0; a < 16; ++a)
    for (int b = 0; b < 16; ++b) {
      bool first_of_pair = true;
      for (int e = 0; e < TBL.nent; ++e) {
        if ((int)TBL.ea[e] == a && (int)TBL.eb[e] == b) {
          s.sa[pos] = (unsigned char)a;
          s.sb[pos] = (unsigned char)b;
          s.sc[pos] = TBL.ec[e];
          s.sp[pos] = TBL.ep[e];
          s.newpair[pos] = first_of_pair;
          s.firstc[pos] = !seen[TBL.ec[e]];
          seen[TBL.ec[e]] = true;
          first_of_pair = false;
          ++pos;
        }
      }
    }
  s.nent = pos;
  return s;
}

constexpr Sched SCH = build_sched();
constexpr int NENT = SCH.nent;
static_assert(SCH.nent == TBL.nent, "schedule must cover all entries");
static_assert(SCH.nent <= 512, "table overflow");

// ---------------- device CG math (fp64, transcribes reference) -------------
__device__ __constant__ double FACT[11] = {
    1., 1., 2., 6., 24., 120., 720., 5040., 40320., 362880., 3628800.};

struct cplx { double re, im; };

__device__ inline double su2_cg(int j1, int m1, int j2, int m2, int j3, int m3) {
  if (m3 != m1 + m2) return 0.0;
  int vmin = -j1 + j2 + m3;
  if (-j1 + m1 > vmin) vmin = -j1 + m1;
  if (0 > vmin) vmin = 0;
  int vmax = j2 + j3 + m1;
  if (j3 - j1 + j2 < vmax) vmax = j3 - j1 + j2;
  if (j3 + m3 < vmax) vmax = j3 + m3;
  double C = (2.0 * j3 + 1.0) *
             (FACT[j3 + j1 - j2] * FACT[j3 - j1 + j2] * FACT[j1 + j2 - j3] *
              FACT[j3 + m3] * FACT[j3 - m3]) /
             (FACT[j1 + j2 + j3 + 1] * FACT[j1 - m1] * FACT[j1 + m1] *
              FACT[j2 - m2] * FACT[j2 + m2]);
  double S = 0.0;
  for (int v = vmin; v <= vmax; ++v) {
    double t = (FACT[j2 + j3 + m1 - v] * FACT[j1 - m1 + v]) /
               (FACT[v] * FACT[j3 - j1 + j2 - v] * FACT[j3 + m3 - v] *
                FACT[v + j1 - j2 - m3]);
    S += (((v + j2 + m2) & 1) ? -1.0 : 1.0) * t;
  }
  return sqrt(C) * S;
}

// q[l+m, l+-|m|] of _change_basis_real_to_complex, incl. global (-i)^l phase.
__device__ inline cplx Qmat(int l, int r, int c) {
  int m = r - l, mc = c - l;
  const double is2 = 0.70710678118654752440;
  double re = 0.0, im = 0.0;
  if (m < 0) {
    if (mc == -m) re = is2;
    else if (mc == m) im = -is2;
  } else if (m == 0) {
    if (mc == 0) re = 1.0;
  } else {
    double s = (m & 1) ? -is2 : is2;
    if (mc == m) re = s;
    else if (mc == -m) im = s;
  }
  cplx out;
  switch (l & 3) {                   // multiply by (-i)^l
    case 0: out.re = re;  out.im = im;  break;
    case 1: out.re = im;  out.im = -re; break;
    case 2: out.re = -re; out.im = -im; break;
    default: out.re = -im; out.im = re; break;
  }
  return out;
}

// One block per path. Computes real-basis CG values and writes
// weights[p]*sqrt(2lo+1)*Creal into the SCHEDULE-ORDERED coefficient slots.
__global__ void cg_setup_kernel(const float* __restrict__ weights,
                                float* __restrict__ wwc) {
  const int p = blockIdx.x;
  const int l1 = TBL.pl1[p], l2 = TBL.pl2[p], lo = TBL.plo[p];
  const int n1 = 2 * l1 + 1, n2 = 2 * l2 + 1, n3 = 2 * lo + 1;
  const int tot = n1 * n2 * n3;
  const int tid = (int)threadIdx.x;
  const int bd = (int)blockDim.x;

  __shared__ double Cs[343];
  __shared__ double Vr[343], Vi[343];
  __shared__ double Ur[343], Ui[343];
  __shared__ double Rr[343];

  // stage 0: SU(2) CG tensor Cs[i,k,n]
  for (int idx = tid; idx < tot; idx += bd) {
    int i = idx / (n2 * n3), r = idx % (n2 * n3);
    int k = r / n3, nn = r % n3;
    Cs[idx] = su2_cg(l1, i - l1, l2, k - l2, lo, nn - lo);
  }
  __syncthreads();

  // stage A: V[i,k,m] = sum_n Cs[i,k,n] * conj(Q3[n,m])
  for (int idx = tid; idx < tot; idx += bd) {
    int i = idx / (n2 * n3), r = idx % (n2 * n3);
    int k = r / n3, m = r % n3;
    double vr = 0.0, vi = 0.0;
    for (int nn = 0; nn < n3; ++nn) {
      double c = Cs[(i * n2 + k) * n3 + nn];
      cplx q = Qmat(lo, nn, m);
      vr += c * q.re;
      vi -= c * q.im;
    }
    Vr[idx] = vr; Vi[idx] = vi;
  }
  __syncthreads();

  // stage B: U[i,l,m] = sum_k Q2[k,l] * V[i,k,m]
  for (int idx = tid; idx < tot; idx += bd) {
    int i = idx / (n2 * n3), r = idx % (n2 * n3);
    int l = r / n3, m = r % n3;
    double ur = 0.0, ui = 0.0;
    for (int k = 0; k < n2; ++k) {
      cplx q = Qmat(l2, k, l);
      double vr = Vr[(i * n2 + k) * n3 + m];
      double vi = Vi[(i * n2 + k) * n3 + m];
      ur += q.re * vr - q.im * vi;
      ui += q.re * vi + q.im * vr;
    }
    Ur[idx] = ur; Ui[idx] = ui;
  }
  __syncthreads();

  // stage C: R[j,l,m] = Re( sum_i Q1[i,j] * U[i,l,m] )
  for (int idx = tid; idx < tot; idx += bd) {
    int j = idx / (n2 * n3), r = idx % (n2 * n3);
    int l = r / n3, m = r % n3;
    double rr = 0.0;
    for (int i = 0; i < n1; ++i) {
      cplx q = Qmat(l1, i, j);
      rr += q.re * Ur[(i * n2 + l) * n3 + m] - q.im * Ui[(i * n2 + l) * n3 + m];
    }
    Rr[idx] = rr;
  }
  __syncthreads();

  // write schedule-ordered coefficients belonging to this path
  const double wsc = (double)weights[p] * sqrt(2.0 * lo + 1.0);
  const int o1 = l1 * l1, o2 = l2 * l2, oo = lo * lo;
  for (int s = tid; s < NENT; s += bd) {
    if ((int)SCH.sp[s] != p) continue;
    int i = (int)SCH.sa[s] - o1;
    int j = (int)SCH.sb[s] - o2;
    int k = (int)SCH.sc[s] - oo;
    wwc[s] = (float)(wsc * Rr[(i * n2 + j) * n3 + k]);
  }
}

// ---------------- main contraction kernel (v1-proven structure) ------------
__global__ __launch_bounds__(256) void tp_kernel(const float* __restrict__ x1,
                                                 const float* __restrict__ x2,
                                                 const float* __restrict__ wwc,
                                                 float* __restrict__ out,
                                                 int n) {
  const int row = (int)blockIdx.x * 256 + (int)threadIdx.x;
  if (row >= n) return;

  const float4* X1 = reinterpret_cast<const float4*>(x1) + (size_t)row * 4;
  const float4* X2 = reinterpret_cast<const float4*>(x2) + (size_t)row * 4;

  float a[16], b[16];
#pragma unroll
  for (int q = 0; q < 4; ++q) {
    float4 t = X1[q];
    a[4 * q + 0] = t.x; a[4 * q + 1] = t.y; a[4 * q + 2] = t.z; a[4 * q + 3] = t.w;
    float4 u = X2[q];
    b[4 * q + 0] = u.x; b[4 * q + 1] = u.y; b[4 * q + 2] = u.z; b[4 * q + 3] = u.w;
  }

  float acc[16];                     // first-touch initialized via firstc
  float t = 0.0f;                    // current (a,b) product

#pragma unroll
  for (int e = 0; e < NENT; ++e) {
    // all SCH.* reads constant-fold after full unroll (v1-proven pattern)
    if (SCH.newpair[e]) t = a[SCH.sa[e]] * b[SCH.sb[e]];
    // wave-uniform read-only load at compile-time offset -> scalar load
    const float w = wwc[e];
    if (SCH.firstc[e]) acc[SCH.sc[e]] = w * t;
    else               acc[SCH.sc[e]] = fmaf(w, t, acc[SCH.sc[e]]);
  }

  v4f* O = reinterpret_cast<v4f*>(out) + (size_t)row * 4;
#pragma unroll
  for (int q = 0; q < 4; ++q) {
    v4f o;
    o.x = acc[4 * q + 0]; o.y = acc[4 * q + 1];
    o.z = acc[4 * q + 2]; o.w = acc[4 * q + 3];
    __builtin_nontemporal_store(o, &O[q]);
  }
}

// ---------------- launch ----------------
extern "C" void kernel_launch(void* const* d_in, const int* in_sizes, int n_in,
                              void* d_out, int out_size, void* d_ws,
                              size_t ws_size, hipStream_t stream) {
  const float* x1 = (const float*)d_in[0];
  const float* x2 = (const float*)d_in[1];
  const float* w  = (const float*)d_in[2];
  float* out = (float*)d_out;
  float* wwc = (float*)d_ws;   // NENT compacted coefficients (schedule order)

  const int n = in_sizes[0] / 16;

  // 1) compute compacted ww3j coefficients (23 tiny blocks)
  cg_setup_kernel<<<dim3(TBL.npaths), dim3(256), 0, stream>>>(w, wwc);

  // 2) sparse per-row contraction (1 row/thread, v1-proven promotion)
  const int grid = (n + 255) / 256;
  tp_kernel<<<dim3(grid), dim3(256), 0, stream>>>(x1, x2, wwc, out, n);
}